// Round 10
// baseline (810.854 us; speedup 1.0000x reference)
//
#include <hip/hip_runtime.h>

#define N_NODES 100000
#define F_IN 512
#define HID 16
#define F_OUT 40

#define NB 784        // buckets = row >> 7 (782 used, 2 empty pads)
#define BSHIFT 7
#define ROWS_PB 128
#define BCAP 4608     // mean 4082 + 8 sigma
#define CUR_PAD 16    // gcursor stride in ints (64B: one counter per line)
#define APAD 17       // LDS acc row stride (pad -> ~2-way bank conflicts)

// ---------------- zero gcursor ----------------
__global__ void k_zero(int* __restrict__ g) {
    int i = blockIdx.x * 256 + threadIdx.x;
    if (i < NB * CUR_PAD) g[i] = 0;
}

// ---------------- pass 1: bucket scatter (packed u32) ----------------
__global__ __launch_bounds__(256) void k_part1(const int* __restrict__ ei, int E,
                                               int* __restrict__ gcursor,
                                               unsigned int* __restrict__ sortbuf) {
    __shared__ int cnt[NB];
    __shared__ int gb[NB];
    int t = threadIdx.x;
    int epb = (E + gridDim.x - 1) / gridDim.x;
    int base = blockIdx.x * epb;
    int lim = min(base + epb, E);
    for (int cbase = base; cbase < lim; cbase += 4096) {
        int cend = min(cbase + 4096, lim);
        for (int i = t; i < NB; i += 256) cnt[i] = 0;
        __syncthreads();
        unsigned int v[16];
        int bkt[16], mi[16];
#pragma unroll
        for (int i = 0; i < 16; ++i) {
            int e = cbase + i * 256 + t;
            bkt[i] = -1;
            if (e < cend) {
                int r = ei[e], c = ei[E + e];
                bkt[i] = r >> BSHIFT;
                v[i] = ((unsigned)(r & (ROWS_PB - 1)) << 17) | (unsigned)c;
                mi[i] = atomicAdd(&cnt[bkt[i]], 1);
            }
        }
        __syncthreads();
        for (int i = t; i < NB; i += 256)
            gb[i] = atomicAdd(&gcursor[i * CUR_PAD], cnt[i]);
        __syncthreads();
#pragma unroll
        for (int i = 0; i < 16; ++i)
            if (bkt[i] >= 0) {
                int idx = gb[bkt[i]] + mi[i];
                if (idx < BCAP) sortbuf[(size_t)bkt[i] * BCAP + idx] = v[i];
            }
        __syncthreads();
    }
}

// ---------------- dinv: per-bucket row histogram -> rsqrt(deg+1) -------------
__global__ __launch_bounds__(256) void k_dinv(const unsigned int* __restrict__ sortbuf,
                                              const int* __restrict__ gcursor,
                                              float* __restrict__ dinv) {
    __shared__ int cnt[ROWS_PB];
    int b = blockIdx.x, t = threadIdx.x;
    if (t < ROWS_PB) cnt[t] = 0;
    __syncthreads();
    int n = min(gcursor[b * CUR_PAD], BCAP);
    const unsigned int* sb = sortbuf + (size_t)b * BCAP;
    for (int i = t; i < n; i += 256) atomicAdd(&cnt[sb[i] >> 17], 1);
    __syncthreads();
    if (t < ROWS_PB) {
        int g = b * ROWS_PB + t;
        if (g < N_NODES) dinv[g] = rsqrtf((float)(cnt[t] + 1));   // +1 self-loop
    }
}

// ---- GEMM1: Hs = (x @ W1) * dinv, 64 rows x 8 wave-uniform K-chunks/block ----
__global__ __launch_bounds__(512) void k_gemm1(const float* __restrict__ x,
                                               const float* __restrict__ W1,
                                               const float* __restrict__ dinv,
                                               float* __restrict__ Hs) {
    __shared__ float red[8 * 64 * APAD];   // 34.8 KB
    int t = threadIdx.x;
    // wave-uniform K-chunk id (64 k each): readfirstlane -> W1 reads stay s_load
    int kc = __builtin_amdgcn_readfirstlane(t >> 6);
    int rl = t & 63;
    int row = blockIdx.x * 64 + rl;

    float acc[HID];
#pragma unroll
    for (int f = 0; f < HID; ++f) acc[f] = 0.0f;

    if (row < N_NODES) {
        const float* xp = x + (size_t)row * F_IN + kc * 64;
        const float* wp = W1 + kc * 64 * HID;
        float4 a0 = *reinterpret_cast<const float4*>(xp);
        float4 a1 = *reinterpret_cast<const float4*>(xp + 4);
        float4 a2 = *reinterpret_cast<const float4*>(xp + 8);
        float4 a3 = *reinterpret_cast<const float4*>(xp + 12);
        for (int k = 0; k < 64; k += 16) {
            float4 n0, n1, n2, n3;
            if (k + 16 < 64) {
                n0 = *reinterpret_cast<const float4*>(xp + k + 16);
                n1 = *reinterpret_cast<const float4*>(xp + k + 20);
                n2 = *reinterpret_cast<const float4*>(xp + k + 24);
                n3 = *reinterpret_cast<const float4*>(xp + k + 28);
            } else {
                n0 = a0; n1 = a1; n2 = a2; n3 = a3;
            }
            float xs[16] = {a0.x, a0.y, a0.z, a0.w, a1.x, a1.y, a1.z, a1.w,
                            a2.x, a2.y, a2.z, a2.w, a3.x, a3.y, a3.z, a3.w};
#pragma unroll
            for (int kk = 0; kk < 16; ++kk) {
                float xv = xs[kk];
#pragma unroll
                for (int f = 0; f < HID; ++f)
                    acc[f] = fmaf(xv, wp[(k + kk) * HID + f], acc[f]);  // s_load
            }
            a0 = n0; a1 = n1; a2 = n2; a3 = n3;
        }
    }
    int base = (kc * 64 + rl) * APAD;
#pragma unroll
    for (int f = 0; f < HID; ++f) red[base + f] = acc[f];
    __syncthreads();
#pragma unroll
    for (int p = 0; p < 2; ++p) {
        int o = p * 512 + t;                  // 0..1023 = 64 rows x 16 f
        int r = o >> 4, f = o & 15;
        int rg = blockIdx.x * 64 + r;
        if (rg < N_NODES) {
            float s = 0.0f;
#pragma unroll
            for (int c = 0; c < 8; ++c) s += red[(c * 64 + r) * APAD + f];
            Hs[(size_t)rg * HID + f] = s * dinv[rg];
        }
    }
}

// -- aggA: per-bucket stream of sortbuf, LDS-atomic accumulate, bias+relu -----
__global__ __launch_bounds__(256) void k_aggA(const unsigned int* __restrict__ sortbuf,
                                              const int* __restrict__ gcursor,
                                              const float* __restrict__ dinv,
                                              const float* __restrict__ Hs,
                                              const float* __restrict__ b1,
                                              float* __restrict__ h1s) {
    __shared__ float acc[ROWS_PB * APAD];   // 8.7 KB
    int b = blockIdx.x, t = threadIdx.x;
    for (int i = t; i < ROWS_PB * APAD; i += 256) acc[i] = 0.0f;
    __syncthreads();
    int n = min(gcursor[b * CUR_PAD], BCAP);
    const unsigned int* sb = sortbuf + (size_t)b * BCAP;
    int f4 = t & 3;
    for (int i = t >> 2; i < n; i += 64) {      // 4 lanes per entry
        unsigned int v = sb[i];
        int c = (int)(v & 0x1FFFFu);
        int lr = (int)(v >> 17);
        float4 hv = *reinterpret_cast<const float4*>(Hs + (size_t)c * HID + f4 * 4);
        float* ap = acc + lr * APAD + f4 * 4;
        atomicAdd(ap + 0, hv.x);
        atomicAdd(ap + 1, hv.y);
        atomicAdd(ap + 2, hv.z);
        atomicAdd(ap + 3, hv.w);
    }
    __syncthreads();
    // epilogue: 2 threads per row, 8 feats each
    int row = t >> 1, fh = (t & 1) * 8;
    int g = b * ROWS_PB + row;
    if (g < N_NODES) {
        float dr = dinv[g];
        float4 o[2];
#pragma unroll
        for (int q = 0; q < 2; ++q) {
            float4 self = *reinterpret_cast<const float4*>(Hs + (size_t)g * HID + fh + q * 4);
            float4 bb = *reinterpret_cast<const float4*>(b1 + fh + q * 4);
            float a0 = acc[row * APAD + fh + q * 4 + 0] + self.x;
            float a1 = acc[row * APAD + fh + q * 4 + 1] + self.y;
            float a2 = acc[row * APAD + fh + q * 4 + 2] + self.z;
            float a3 = acc[row * APAD + fh + q * 4 + 3] + self.w;
            o[q].x = fmaxf(a0 * dr + bb.x, 0.f) * dr;
            o[q].y = fmaxf(a1 * dr + bb.y, 0.f) * dr;
            o[q].z = fmaxf(a2 * dr + bb.z, 0.f) * dr;
            o[q].w = fmaxf(a3 * dr + bb.w, 0.f) * dr;
        }
        *reinterpret_cast<float4*>(h1s + (size_t)g * HID + fh) = o[0];
        *reinterpret_cast<float4*>(h1s + (size_t)g * HID + fh + 4) = o[1];
    }
}

// -- aggB: per-bucket accumulate of h1s, fused 16x40 W2 GEMM + bias -> out ----
__global__ __launch_bounds__(256) void k_aggB(const unsigned int* __restrict__ sortbuf,
                                              const int* __restrict__ gcursor,
                                              const float* __restrict__ dinv,
                                              const float* __restrict__ h1s,
                                              const float* __restrict__ W2,
                                              const float* __restrict__ b2,
                                              float* __restrict__ out) {
    __shared__ float acc[ROWS_PB * APAD];       // 8.7 KB
    __shared__ float wrow[ROWS_PB][HID];        // 8 KB pre-W2 vectors
    int b = blockIdx.x, t = threadIdx.x;
    for (int i = t; i < ROWS_PB * APAD; i += 256) acc[i] = 0.0f;
    __syncthreads();
    int n = min(gcursor[b * CUR_PAD], BCAP);
    const unsigned int* sb = sortbuf + (size_t)b * BCAP;
    int f4 = t & 3;
    for (int i = t >> 2; i < n; i += 64) {
        unsigned int v = sb[i];
        int c = (int)(v & 0x1FFFFu);
        int lr = (int)(v >> 17);
        float4 hv = *reinterpret_cast<const float4*>(h1s + (size_t)c * HID + f4 * 4);
        float* ap = acc + lr * APAD + f4 * 4;
        atomicAdd(ap + 0, hv.x);
        atomicAdd(ap + 1, hv.y);
        atomicAdd(ap + 2, hv.z);
        atomicAdd(ap + 3, hv.w);
    }
    __syncthreads();
    int row = t >> 1, fh = (t & 1) * 8;
    int g = b * ROWS_PB + row;
    if (g < N_NODES) {
        float dr = dinv[g];
#pragma unroll
        for (int f = 0; f < 8; ++f) {
            int ff = fh + f;
            wrow[row][ff] = (acc[row * APAD + ff] + h1s[(size_t)g * HID + ff]) * dr;
        }
    }
    __syncthreads();
    // W2 epilogue: 2 threads per row, 20 outputs each (5 x float4)
    int half = t & 1;
    if (g < N_NODES) {
        float4 o4[5];
#pragma unroll
        for (int q = 0; q < 5; ++q)
            o4[q] = *reinterpret_cast<const float4*>(b2 + half * 20 + q * 4);
#pragma unroll
        for (int k = 0; k < HID; ++k) {
            float wk = wrow[row][k];
            const float* w2p = W2 + k * F_OUT + half * 20;
#pragma unroll
            for (int q = 0; q < 5; ++q) {
                float4 wv = *reinterpret_cast<const float4*>(w2p + q * 4);
                o4[q].x = fmaf(wk, wv.x, o4[q].x);
                o4[q].y = fmaf(wk, wv.y, o4[q].y);
                o4[q].z = fmaf(wk, wv.z, o4[q].z);
                o4[q].w = fmaf(wk, wv.w, o4[q].w);
            }
        }
#pragma unroll
        for (int q = 0; q < 5; ++q)
            *reinterpret_cast<float4*>(out + (size_t)g * F_OUT + half * 20 + q * 4) = o4[q];
    }
}

// ---------------- launch ----------------
extern "C" void kernel_launch(void* const* d_in, const int* in_sizes, int n_in,
                              void* d_out, int out_size, void* d_ws, size_t ws_size,
                              hipStream_t stream) {
    const float* x  = (const float*)d_in[0];
    const int* ei   = (const int*)d_in[1];      // int32 [2][E]
    const float* W1 = (const float*)d_in[2];
    const float* b1 = (const float*)d_in[3];
    const float* W2 = (const float*)d_in[4];
    const float* b2 = (const float*)d_in[5];
    float* out = (float*)d_out;
    const int E = in_sizes[1] / 2;

    // ws layout (4B units, 64B-aligned sections)
    int* gcursor          = (int*)d_ws;                      // 784*16 = 12544
    float* dinv           = (float*)(gcursor + 12544);       // 100000 -> pad 100032
    unsigned int* sortbuf = (unsigned int*)(dinv + 100032);  // 784*4608 = 3,612,672
    float* Hs             = (float*)(sortbuf + 3612672);     // N*16 = 1,600,000
    float* h1s            = Hs + 1600000;                    // N*16
    // total ~27.7 MB

    const int nbG = (N_NODES + 63) / 64;   // 1563

    k_zero<<<(NB * CUR_PAD + 255) / 256, 256, 0, stream>>>(gcursor);
    k_part1<<<1024, 256, 0, stream>>>(ei, E, gcursor, sortbuf);
    k_dinv<<<NB, 256, 0, stream>>>(sortbuf, gcursor, dinv);

    k_gemm1<<<nbG, 512, 0, stream>>>(x, W1, dinv, Hs);

    k_aggA<<<NB, 256, 0, stream>>>(sortbuf, gcursor, dinv, Hs, b1, h1s);
    k_aggB<<<NB, 256, 0, stream>>>(sortbuf, gcursor, dinv, h1s, W2, b2, out);
}

// Round 11
// 344.544 us; speedup vs baseline: 2.3534x; 2.3534x over previous
//
#include <hip/hip_runtime.h>

#define N_NODES 100000
#define F_IN 512
#define HID 16
#define F_OUT 40

#define NB 784        // buckets = row >> 7
#define BSHIFT 7
#define ROWS_PB 128
#define BCAP 4608     // mean 4082 + 8 sigma
#define CUR_PAD 16    // gcursor stride in ints (64B: one counter per line)
#define APAD 17

// ---------------- zero gcursor + cnt ----------------
__global__ void k_zero(int* __restrict__ gcursor, int* __restrict__ cnt) {
    int i = blockIdx.x * 256 + threadIdx.x;
    if (i < NB * CUR_PAD) gcursor[i] = 0;
    if (i < NB * ROWS_PB) cnt[i] = 0;     // covers rows >= N_NODES with 0
}

// ------- pass 1: bucket scatter (packed u32) + global degree count ----------
__global__ __launch_bounds__(256) void k_part1(const int* __restrict__ ei, int E,
                                               int* __restrict__ gcursor,
                                               unsigned int* __restrict__ sortbuf,
                                               int* __restrict__ cnt) {
    __shared__ int lcnt[NB];
    __shared__ int gb[NB];
    int t = threadIdx.x;
    int epb = (E + gridDim.x - 1) / gridDim.x;
    int base = blockIdx.x * epb;
    int lim = min(base + epb, E);
    for (int cbase = base; cbase < lim; cbase += 4096) {
        int cend = min(cbase + 4096, lim);
        for (int i = t; i < NB; i += 256) lcnt[i] = 0;
        __syncthreads();
        unsigned int v[16];
        int bkt[16], mi[16];
#pragma unroll
        for (int i = 0; i < 16; ++i) {
            int e = cbase + i * 256 + t;
            bkt[i] = -1;
            if (e < cend) {
                int r = ei[e], c = ei[E + e];
                bkt[i] = r >> BSHIFT;
                v[i] = ((unsigned)(r & (ROWS_PB - 1)) << 17) | (unsigned)c;
                mi[i] = atomicAdd(&lcnt[bkt[i]], 1);
                atomicAdd(&cnt[r], 1);            // global degree (TCC-side, cheap)
            }
        }
        __syncthreads();
        for (int i = t; i < NB; i += 256)
            gb[i] = atomicAdd(&gcursor[i * CUR_PAD], lcnt[i]);
        __syncthreads();
#pragma unroll
        for (int i = 0; i < 16; ++i)
            if (bkt[i] >= 0) {
                int idx = gb[bkt[i]] + mi[i];
                if (idx < BCAP) sortbuf[(size_t)bkt[i] * BCAP + idx] = v[i];
            }
        __syncthreads();
    }
}

// ---- pass 2: CSR build; row starts from global cnt (1 LDS atomic/edge) ------
__global__ __launch_bounds__(256) void k_build(const unsigned int* __restrict__ sortbuf,
                                               const int* __restrict__ gcursor,
                                               const int* __restrict__ cnt,
                                               int* __restrict__ rowptr,
                                               float* __restrict__ dinv,
                                               int* __restrict__ colv) {
    __shared__ int bb[NB];          // exclusive bucket bases
    __shared__ int s[256];
    __shared__ int rstart[ROWS_PB];
    __shared__ int cur[ROWS_PB];
    int b = blockIdx.x, t = threadIdx.x;

    // in-block scan of 784 bucket totals (4 per thread, 196 threads)
    int l0 = 0, l1 = 0, l2 = 0, l3 = 0;
    if (t < 196) {
        l0 = min(gcursor[(t * 4 + 0) * CUR_PAD], BCAP);
        l1 = min(gcursor[(t * 4 + 1) * CUR_PAD], BCAP);
        l2 = min(gcursor[(t * 4 + 2) * CUR_PAD], BCAP);
        l3 = min(gcursor[(t * 4 + 3) * CUR_PAD], BCAP);
    }
    int part = l0 + l1 + l2 + l3;
    s[t] = part;
    __syncthreads();
    for (int off = 1; off < 256; off <<= 1) {
        int a = (t >= off) ? s[t - off] : 0;
        __syncthreads();
        s[t] += a;
        __syncthreads();
    }
    if (t < 196) {
        int ex = s[t] - part;
        bb[t * 4 + 0] = ex;
        bb[t * 4 + 1] = ex + l0;
        bb[t * 4 + 2] = ex + l0 + l1;
        bb[t * 4 + 3] = ex + l0 + l1 + l2;
    }
    __syncthreads();
    int gbase = bb[b];
    int n = min(gcursor[b * CUR_PAD], BCAP);
    if (b == 0 && t == 0) rowptr[N_NODES] = s[255];

    // row starts from global degree counts (no LDS histogram)
    int c0 = (t < ROWS_PB) ? cnt[b * ROWS_PB + t] : 0;
    s[t] = (t < ROWS_PB) ? c0 : 0;
    __syncthreads();
    for (int off = 1; off < 256; off <<= 1) {
        int a = (t >= off) ? s[t - off] : 0;
        __syncthreads();
        s[t] += a;
        __syncthreads();
    }
    if (t < ROWS_PB) {
        int ex = s[t] - c0;
        rstart[t] = ex;
        cur[t] = 0;
        int g = b * ROWS_PB + t;
        if (g < N_NODES) {
            rowptr[g] = gbase + ex;
            dinv[g] = rsqrtf((float)(c0 + 1));   // +1 self-loop
        }
    }
    __syncthreads();
    const unsigned int* sb = sortbuf + (size_t)b * BCAP;
    for (int i = t; i < n; i += 256) {
        unsigned int v = sb[i];
        int lr = v >> 17;
        int pos = atomicAdd(&cur[lr], 1);        // the only per-edge LDS atomic
        colv[gbase + rstart[lr] + pos] = (int)(v & 0x1FFFFu);
    }
}

// ---- GEMM1: Hs = (x @ W1) * dinv, 64 rows x 8 wave-uniform K-chunks/block ----
__global__ __launch_bounds__(512) void k_gemm1(const float* __restrict__ x,
                                               const float* __restrict__ W1,
                                               const float* __restrict__ dinv,
                                               float* __restrict__ Hs) {
    __shared__ float red[8 * 64 * APAD];   // 34.8 KB
    int t = threadIdx.x;
    // wave-uniform K-chunk id (64 k each): readfirstlane -> W1 reads stay s_load
    int kc = __builtin_amdgcn_readfirstlane(t >> 6);
    int rl = t & 63;
    int row = blockIdx.x * 64 + rl;

    float acc[HID];
#pragma unroll
    for (int f = 0; f < HID; ++f) acc[f] = 0.0f;

    if (row < N_NODES) {
        const float* xp = x + (size_t)row * F_IN + kc * 64;
        const float* wp = W1 + kc * 64 * HID;
        float4 a0 = *reinterpret_cast<const float4*>(xp);
        float4 a1 = *reinterpret_cast<const float4*>(xp + 4);
        float4 a2 = *reinterpret_cast<const float4*>(xp + 8);
        float4 a3 = *reinterpret_cast<const float4*>(xp + 12);
        for (int k = 0; k < 64; k += 16) {
            float4 n0, n1, n2, n3;
            if (k + 16 < 64) {
                n0 = *reinterpret_cast<const float4*>(xp + k + 16);
                n1 = *reinterpret_cast<const float4*>(xp + k + 20);
                n2 = *reinterpret_cast<const float4*>(xp + k + 24);
                n3 = *reinterpret_cast<const float4*>(xp + k + 28);
            } else {
                n0 = a0; n1 = a1; n2 = a2; n3 = a3;
            }
            float xs[16] = {a0.x, a0.y, a0.z, a0.w, a1.x, a1.y, a1.z, a1.w,
                            a2.x, a2.y, a2.z, a2.w, a3.x, a3.y, a3.z, a3.w};
#pragma unroll
            for (int kk = 0; kk < 16; ++kk) {
                float xv = xs[kk];
#pragma unroll
                for (int f = 0; f < HID; ++f)
                    acc[f] = fmaf(xv, wp[(k + kk) * HID + f], acc[f]);  // s_load
            }
            a0 = n0; a1 = n1; a2 = n2; a3 = n3;
        }
    }
    int base = (kc * 64 + rl) * APAD;
#pragma unroll
    for (int f = 0; f < HID; ++f) red[base + f] = acc[f];
    __syncthreads();
#pragma unroll
    for (int p = 0; p < 2; ++p) {
        int o = p * 512 + t;                  // 0..1023 = 64 rows x 16 f
        int r = o >> 4, f = o & 15;
        int rg = blockIdx.x * 64 + r;
        if (rg < N_NODES) {
            float s = 0.0f;
#pragma unroll
            for (int c = 0; c < 8; ++c) s += red[(c * 64 + r) * APAD + f];
            Hs[(size_t)rg * HID + f] = s * dinv[rg];
        }
    }
}

// -- agg1: wave/node pull, float4 gathers, scalar-hoisted row meta ------------
__global__ __launch_bounds__(256) void k_agg1(const int* __restrict__ rowptr,
                                              const int* __restrict__ colv,
                                              const float* __restrict__ dinv,
                                              const float* __restrict__ Hs,
                                              const float* __restrict__ b1,
                                              float* __restrict__ h1s) {
    int wid = __builtin_amdgcn_readfirstlane((blockIdx.x * 256 + threadIdx.x) >> 6);
    if (wid >= N_NODES) return;
    int lane = threadIdx.x & 63;
    int f4 = lane & 3, sub = lane >> 2;
    int beg = rowptr[wid], end = rowptr[wid + 1];   // s_load (wid scalar)
    float dr = dinv[wid];                            // s_load
    float4 acc = make_float4(0.f, 0.f, 0.f, 0.f);
    for (int j = beg + sub; j < end; j += 16) {
        int c = colv[j];
        float4 hv = *reinterpret_cast<const float4*>(Hs + (size_t)c * HID + f4 * 4);
        acc.x += hv.x; acc.y += hv.y; acc.z += hv.z; acc.w += hv.w;
    }
#pragma unroll
    for (int d = 4; d < 64; d <<= 1) {
        acc.x += __shfl_xor(acc.x, d);
        acc.y += __shfl_xor(acc.y, d);
        acc.z += __shfl_xor(acc.z, d);
        acc.w += __shfl_xor(acc.w, d);
    }
    if (sub == 0) {
        float4 self = *reinterpret_cast<const float4*>(Hs + (size_t)wid * HID + f4 * 4);
        float4 bb = *reinterpret_cast<const float4*>(b1 + f4 * 4);
        float4 o;
        o.x = fmaxf((acc.x + self.x) * dr + bb.x, 0.f) * dr;
        o.y = fmaxf((acc.y + self.y) * dr + bb.y, 0.f) * dr;
        o.z = fmaxf((acc.z + self.z) * dr + bb.z, 0.f) * dr;
        o.w = fmaxf((acc.w + self.w) * dr + bb.w, 0.f) * dr;
        *reinterpret_cast<float4*>(h1s + (size_t)wid * HID + f4 * 4) = o;
    }
}

// -- agg2: wave/node pull of h1s (float4), fused 16x40 GEMM + bias -> out -----
__global__ __launch_bounds__(256) void k_agg2(const int* __restrict__ rowptr,
                                              const int* __restrict__ colv,
                                              const float* __restrict__ dinv,
                                              const float* __restrict__ h1s,
                                              const float* __restrict__ W2,
                                              const float* __restrict__ b2,
                                              float* __restrict__ out) {
    int wid = __builtin_amdgcn_readfirstlane((blockIdx.x * 256 + threadIdx.x) >> 6);
    if (wid >= N_NODES) return;
    int lane = threadIdx.x & 63;
    int f4 = lane & 3, sub = lane >> 2;
    int beg = rowptr[wid], end = rowptr[wid + 1];   // s_load
    float dr = dinv[wid];                            // s_load
    float4 acc = make_float4(0.f, 0.f, 0.f, 0.f);
    for (int j = beg + sub; j < end; j += 16) {
        int c = colv[j];
        float4 hv = *reinterpret_cast<const float4*>(h1s + (size_t)c * HID + f4 * 4);
        acc.x += hv.x; acc.y += hv.y; acc.z += hv.z; acc.w += hv.w;
    }
#pragma unroll
    for (int d = 4; d < 64; d <<= 1) {
        acc.x += __shfl_xor(acc.x, d);
        acc.y += __shfl_xor(acc.y, d);
        acc.z += __shfl_xor(acc.z, d);
        acc.w += __shfl_xor(acc.w, d);
    }
    float4 self = *reinterpret_cast<const float4*>(h1s + (size_t)wid * HID + f4 * 4);
    float4 w4;
    w4.x = (acc.x + self.x) * dr;
    w4.y = (acc.y + self.y) * dr;
    w4.z = (acc.z + self.z) * dr;
    w4.w = (acc.w + self.w) * dr;
    if (lane < F_OUT) {
        float o = b2[lane];
#pragma unroll
        for (int k = 0; k < HID; ++k) {
            float comp = (k & 3) == 0 ? w4.x : (k & 3) == 1 ? w4.y
                        : (k & 3) == 2 ? w4.z : w4.w;
            float wk = __shfl(comp, k >> 2);   // lane k>>2 has f4 == k>>2
            o = fmaf(wk, W2[k * F_OUT + lane], o);
        }
        out[(size_t)wid * F_OUT + lane] = o;
    }
}

// ---------------- launch ----------------
extern "C" void kernel_launch(void* const* d_in, const int* in_sizes, int n_in,
                              void* d_out, int out_size, void* d_ws, size_t ws_size,
                              hipStream_t stream) {
    const float* x  = (const float*)d_in[0];
    const int* ei   = (const int*)d_in[1];      // int32 [2][E]
    const float* W1 = (const float*)d_in[2];
    const float* b1 = (const float*)d_in[3];
    const float* W2 = (const float*)d_in[4];
    const float* b2 = (const float*)d_in[5];
    float* out = (float*)d_out;
    const int E = in_sizes[1] / 2;

    // ws layout (4B units, 64B-aligned sections)
    int* gcursor          = (int*)d_ws;                      // 12544
    int* cnt              = gcursor + 12544;                 // NB*ROWS_PB = 100352
    int* rowptr           = cnt + 100352;                    // 100001 -> pad 100016
    float* dinv           = (float*)(rowptr + 100016);       // 100000 -> pad 100032
    int* colv             = (int*)(dinv + 100032);           // 3,200,000
    unsigned int* sortbuf = (unsigned int*)(colv + 3200000); // 784*4608 = 3,612,672
    float* Hs             = (float*)sortbuf;                 // alias: dead after build
    float* h1s            = (float*)(sortbuf + 3612672);     // N*16
    // total ~34.9 MB

    const int nbW = (N_NODES * 64 + 255) / 256;    // 25000 (wave per node)
    const int nbG = (N_NODES + 63) / 64;           // 1563

    k_zero<<<(NB * ROWS_PB + 255) / 256, 256, 0, stream>>>(gcursor, cnt);
    k_part1<<<1024, 256, 0, stream>>>(ei, E, gcursor, sortbuf, cnt);
    k_build<<<NB, 256, 0, stream>>>(sortbuf, gcursor, cnt, rowptr, dinv, colv);

    k_gemm1<<<nbG, 512, 0, stream>>>(x, W1, dinv, Hs);

    k_agg1<<<nbW, 256, 0, stream>>>(rowptr, colv, dinv, Hs, b1, h1s);
    k_agg2<<<nbW, 256, 0, stream>>>(rowptr, colv, dinv, h1s, W2, b2, out);
}

// Round 12
// 218.518 us; speedup vs baseline: 3.7107x; 1.5767x over previous
//
#include <hip/hip_runtime.h>

#define N_NODES 100000
#define F_IN 512
#define HID 16
#define F_OUT 40

#define NB 784        // buckets = row >> 7
#define BSHIFT 7
#define ROWS_PB 128
#define BCAP 4608     // mean 4096 + 8 sigma
#define CUR_PAD 16    // gcursor stride in ints (64B line per counter)
#define APAD 17
#define PARTB 512     // part1 blocks inside k_fat

// ---------------- zero gcursor ----------------
__global__ void k_zero(int* __restrict__ g) {
    int i = blockIdx.x * 256 + threadIdx.x;
    if (i < NB * CUR_PAD) g[i] = 0;
}

// ---- FAT: blocks [0,PARTB) = edge bucket-scatter; rest = GEMM1 (raw Hs) ----
__global__ __launch_bounds__(512) void k_fat(const float* __restrict__ x,
                                             const float* __restrict__ W1,
                                             const int* __restrict__ ei, int E,
                                             int* __restrict__ gcursor,
                                             unsigned int* __restrict__ sortbuf,
                                             float* __restrict__ Hs) {
    __shared__ float smem[8 * 64 * APAD];   // 34.8 KB, unioned across paths
    int t = threadIdx.x;
    if (blockIdx.x < PARTB) {
        // ---------------- part1: bucket scatter (packed u32) ----------------
        int* lcnt = (int*)smem;         // NB
        int* gb   = lcnt + NB;          // NB
        int epb = (E + PARTB - 1) / PARTB;          // 6250
        int base = blockIdx.x * epb;
        int lim = min(base + epb, E);
        for (int cbase = base; cbase < lim; cbase += 4096) {
            int cend = min(cbase + 4096, lim);
            for (int i = t; i < NB; i += 512) lcnt[i] = 0;
            __syncthreads();
            unsigned int v[8]; int bkt[8], mi[8];
#pragma unroll
            for (int i = 0; i < 8; ++i) {
                int e = cbase + i * 512 + t;
                bkt[i] = -1;
                if (e < cend) {
                    int r = ei[e], c = ei[E + e];
                    bkt[i] = r >> BSHIFT;
                    v[i] = ((unsigned)(r & (ROWS_PB - 1)) << 17) | (unsigned)c;
                    mi[i] = atomicAdd(&lcnt[bkt[i]], 1);
                }
            }
            __syncthreads();
            for (int i = t; i < NB; i += 512)
                gb[i] = atomicAdd(&gcursor[i * CUR_PAD], lcnt[i]);
            __syncthreads();
#pragma unroll
            for (int i = 0; i < 8; ++i)
                if (bkt[i] >= 0) {
                    int idx = gb[bkt[i]] + mi[i];
                    if (idx < BCAP) sortbuf[(size_t)bkt[i] * BCAP + idx] = v[i];
                }
            __syncthreads();
        }
    } else {
        // ------- GEMM1: Hs_raw = x @ W1, 64 rows x 8 uniform K-chunks -------
        float* red = smem;
        int kc = __builtin_amdgcn_readfirstlane(t >> 6);   // s_load path for W1
        int rl = t & 63;
        int bid = blockIdx.x - PARTB;
        int row = bid * 64 + rl;

        float acc[HID];
#pragma unroll
        for (int f = 0; f < HID; ++f) acc[f] = 0.0f;

        if (row < N_NODES) {
            const float* xp = x + (size_t)row * F_IN + kc * 64;
            const float* wp = W1 + kc * 64 * HID;
            float4 a0 = *reinterpret_cast<const float4*>(xp);
            float4 a1 = *reinterpret_cast<const float4*>(xp + 4);
            float4 a2 = *reinterpret_cast<const float4*>(xp + 8);
            float4 a3 = *reinterpret_cast<const float4*>(xp + 12);
            for (int k = 0; k < 64; k += 16) {
                float4 n0, n1, n2, n3;
                if (k + 16 < 64) {
                    n0 = *reinterpret_cast<const float4*>(xp + k + 16);
                    n1 = *reinterpret_cast<const float4*>(xp + k + 20);
                    n2 = *reinterpret_cast<const float4*>(xp + k + 24);
                    n3 = *reinterpret_cast<const float4*>(xp + k + 28);
                } else {
                    n0 = a0; n1 = a1; n2 = a2; n3 = a3;
                }
                float xs[16] = {a0.x, a0.y, a0.z, a0.w, a1.x, a1.y, a1.z, a1.w,
                                a2.x, a2.y, a2.z, a2.w, a3.x, a3.y, a3.z, a3.w};
#pragma unroll
                for (int kk = 0; kk < 16; ++kk) {
                    float xv = xs[kk];
#pragma unroll
                    for (int f = 0; f < HID; ++f)
                        acc[f] = fmaf(xv, wp[(k + kk) * HID + f], acc[f]);  // s_load
                }
                a0 = n0; a1 = n1; a2 = n2; a3 = n3;
            }
        }
        int base = (kc * 64 + rl) * APAD;
#pragma unroll
        for (int f = 0; f < HID; ++f) red[base + f] = acc[f];
        __syncthreads();
#pragma unroll
        for (int p = 0; p < 2; ++p) {
            int o = p * 512 + t;
            int r = o >> 4, f = o & 15;
            int rg = bid * 64 + r;
            if (rg < N_NODES) {
                float s = 0.0f;
#pragma unroll
                for (int c = 0; c < 8; ++c) s += red[(c * 64 + r) * APAD + f];
                Hs[(size_t)rg * HID + f] = s;       // raw; scaled in k_build
            }
        }
    }
}

// -- build: bucket scan + LDS hist + scatter; fused dinv + Hs scaling ---------
__global__ __launch_bounds__(256) void k_build(const unsigned int* __restrict__ sortbuf,
                                               const int* __restrict__ gcursor,
                                               int* __restrict__ rowptr,
                                               float* __restrict__ dinv,
                                               int* __restrict__ colv,
                                               float* __restrict__ Hs) {
    __shared__ int bb[NB];
    __shared__ int s[256];
    __shared__ int hist[ROWS_PB];
    __shared__ int rstart[ROWS_PB];
    __shared__ int cur[ROWS_PB];
    __shared__ float sdinv[ROWS_PB];
    int b = blockIdx.x, t = threadIdx.x;

    // bucket-base scan (784 totals, 4/thread over 196 threads)
    int l0 = 0, l1 = 0, l2 = 0, l3 = 0;
    if (t < 196) {
        l0 = min(gcursor[(t * 4 + 0) * CUR_PAD], BCAP);
        l1 = min(gcursor[(t * 4 + 1) * CUR_PAD], BCAP);
        l2 = min(gcursor[(t * 4 + 2) * CUR_PAD], BCAP);
        l3 = min(gcursor[(t * 4 + 3) * CUR_PAD], BCAP);
    }
    int part = l0 + l1 + l2 + l3;
    s[t] = part;
    __syncthreads();
    for (int off = 1; off < 256; off <<= 1) {
        int a = (t >= off) ? s[t - off] : 0;
        __syncthreads();
        s[t] += a;
        __syncthreads();
    }
    if (t < 196) {
        int ex = s[t] - part;
        bb[t * 4 + 0] = ex;
        bb[t * 4 + 1] = ex + l0;
        bb[t * 4 + 2] = ex + l0 + l1;
        bb[t * 4 + 3] = ex + l0 + l1 + l2;
    }
    if (t < ROWS_PB) hist[t] = 0;
    __syncthreads();
    int gbase = bb[b];
    int n = min(gcursor[b * CUR_PAD], BCAP);
    if (b == 0 && t == 0) rowptr[N_NODES] = s[255];

    // per-row histogram
    const unsigned int* sb = sortbuf + (size_t)b * BCAP;
    for (int i = t; i < n; i += 256) atomicAdd(&hist[sb[i] >> 17], 1);
    __syncthreads();
    int c0 = (t < ROWS_PB) ? hist[t] : 0;
    s[t] = c0;
    __syncthreads();
    for (int off = 1; off < 256; off <<= 1) {
        int a = (t >= off) ? s[t - off] : 0;
        __syncthreads();
        s[t] += a;
        __syncthreads();
    }
    if (t < ROWS_PB) {
        int ex = s[t] - c0;
        rstart[t] = ex;
        cur[t] = 0;
        float dv = rsqrtf((float)(c0 + 1));   // +1 self-loop
        sdinv[t] = dv;
        int g = b * ROWS_PB + t;
        if (g < N_NODES) {
            rowptr[g] = gbase + ex;
            dinv[g] = dv;
        }
    }
    __syncthreads();
    // scatter into row-sorted colv
    for (int i = t; i < n; i += 256) {
        unsigned int v = sb[i];
        int lr = v >> 17;
        int pos = atomicAdd(&cur[lr], 1);
        colv[gbase + rstart[lr] + pos] = (int)(v & 0x1FFFFu);
    }
    __syncthreads();
    // scale this bucket's Hs rows: Hs *= dinv (gemm wrote raw)
    for (int i = t; i < ROWS_PB * 4; i += 256) {
        int row = i >> 2, q = i & 3;
        int g = b * ROWS_PB + row;
        if (g < N_NODES) {
            float4* p = reinterpret_cast<float4*>(Hs + (size_t)g * HID + q * 4);
            float4 vv = *p;
            float dv = sdinv[row];
            vv.x *= dv; vv.y *= dv; vv.z *= dv; vv.w *= dv;
            *p = vv;
        }
    }
}

// -- agg1: wave/node pull, float4 gathers, scalar-hoisted row meta ------------
__global__ __launch_bounds__(256) void k_agg1(const int* __restrict__ rowptr,
                                              const int* __restrict__ colv,
                                              const float* __restrict__ dinv,
                                              const float* __restrict__ Hs,
                                              const float* __restrict__ b1,
                                              float* __restrict__ h1s) {
    int wid = __builtin_amdgcn_readfirstlane((blockIdx.x * 256 + threadIdx.x) >> 6);
    if (wid >= N_NODES) return;
    int lane = threadIdx.x & 63;
    int f4 = lane & 3, sub = lane >> 2;
    int beg = rowptr[wid], end = rowptr[wid + 1];   // s_load (wid scalar)
    float dr = dinv[wid];                            // s_load
    float4 acc = make_float4(0.f, 0.f, 0.f, 0.f);
    for (int j = beg + sub; j < end; j += 16) {
        int c = colv[j];
        float4 hv = *reinterpret_cast<const float4*>(Hs + (size_t)c * HID + f4 * 4);
        acc.x += hv.x; acc.y += hv.y; acc.z += hv.z; acc.w += hv.w;
    }
#pragma unroll
    for (int d = 4; d < 64; d <<= 1) {
        acc.x += __shfl_xor(acc.x, d);
        acc.y += __shfl_xor(acc.y, d);
        acc.z += __shfl_xor(acc.z, d);
        acc.w += __shfl_xor(acc.w, d);
    }
    if (sub == 0) {
        float4 self = *reinterpret_cast<const float4*>(Hs + (size_t)wid * HID + f4 * 4);
        float4 bb = *reinterpret_cast<const float4*>(b1 + f4 * 4);
        float4 o;
        o.x = fmaxf((acc.x + self.x) * dr + bb.x, 0.f) * dr;
        o.y = fmaxf((acc.y + self.y) * dr + bb.y, 0.f) * dr;
        o.z = fmaxf((acc.z + self.z) * dr + bb.z, 0.f) * dr;
        o.w = fmaxf((acc.w + self.w) * dr + bb.w, 0.f) * dr;
        *reinterpret_cast<float4*>(h1s + (size_t)wid * HID + f4 * 4) = o;
    }
}

// -- agg2: wave/node pull of h1s (float4), fused 16x40 GEMM + bias -> out -----
__global__ __launch_bounds__(256) void k_agg2(const int* __restrict__ rowptr,
                                              const int* __restrict__ colv,
                                              const float* __restrict__ dinv,
                                              const float* __restrict__ h1s,
                                              const float* __restrict__ W2,
                                              const float* __restrict__ b2,
                                              float* __restrict__ out) {
    int wid = __builtin_amdgcn_readfirstlane((blockIdx.x * 256 + threadIdx.x) >> 6);
    if (wid >= N_NODES) return;
    int lane = threadIdx.x & 63;
    int f4 = lane & 3, sub = lane >> 2;
    int beg = rowptr[wid], end = rowptr[wid + 1];   // s_load
    float dr = dinv[wid];                            // s_load
    float4 acc = make_float4(0.f, 0.f, 0.f, 0.f);
    for (int j = beg + sub; j < end; j += 16) {
        int c = colv[j];
        float4 hv = *reinterpret_cast<const float4*>(h1s + (size_t)c * HID + f4 * 4);
        acc.x += hv.x; acc.y += hv.y; acc.z += hv.z; acc.w += hv.w;
    }
#pragma unroll
    for (int d = 4; d < 64; d <<= 1) {
        acc.x += __shfl_xor(acc.x, d);
        acc.y += __shfl_xor(acc.y, d);
        acc.z += __shfl_xor(acc.z, d);
        acc.w += __shfl_xor(acc.w, d);
    }
    float4 self = *reinterpret_cast<const float4*>(h1s + (size_t)wid * HID + f4 * 4);
    float4 w4;
    w4.x = (acc.x + self.x) * dr;
    w4.y = (acc.y + self.y) * dr;
    w4.z = (acc.z + self.z) * dr;
    w4.w = (acc.w + self.w) * dr;
    if (lane < F_OUT) {
        float o = b2[lane];
#pragma unroll
        for (int k = 0; k < HID; ++k) {
            float comp = (k & 3) == 0 ? w4.x : (k & 3) == 1 ? w4.y
                        : (k & 3) == 2 ? w4.z : w4.w;
            float wk = __shfl(comp, k >> 2);   // lane k>>2 holds f4 == k>>2
            o = fmaf(wk, W2[k * F_OUT + lane], o);
        }
        out[(size_t)wid * F_OUT + lane] = o;
    }
}

// ---------------- launch ----------------
extern "C" void kernel_launch(void* const* d_in, const int* in_sizes, int n_in,
                              void* d_out, int out_size, void* d_ws, size_t ws_size,
                              hipStream_t stream) {
    const float* x  = (const float*)d_in[0];
    const int* ei   = (const int*)d_in[1];      // int32 [2][E]
    const float* W1 = (const float*)d_in[2];
    const float* b1 = (const float*)d_in[3];
    const float* W2 = (const float*)d_in[4];
    const float* b2 = (const float*)d_in[5];
    float* out = (float*)d_out;
    const int E = in_sizes[1] / 2;

    // ws layout (4B units)
    int* gcursor          = (int*)d_ws;                      // 12544
    int* rowptr           = gcursor + 12544;                 // 100016
    float* dinv           = (float*)(rowptr + 100016);       // 100032
    int* colv             = (int*)(dinv + 100032);           // 3,200,000
    unsigned int* sortbuf = (unsigned int*)(colv + 3200000); // 3,612,672
    float* h1s            = (float*)sortbuf;                 // alias: dead after build
    float* Hs             = (float*)(sortbuf + 3612672);     // 1,600,000
    // total ~34.5 MB

    const int nbW = (N_NODES * 64 + 255) / 256;    // 25000 (wave per node)
    const int nbG = (N_NODES + 63) / 64;           // 1563

    k_zero<<<(NB * CUR_PAD + 255) / 256, 256, 0, stream>>>(gcursor);
    k_fat<<<PARTB + nbG, 512, 0, stream>>>(x, W1, ei, E, gcursor, sortbuf, Hs);
    k_build<<<NB, 256, 0, stream>>>(sortbuf, gcursor, rowptr, dinv, colv, Hs);
    k_agg1<<<nbW, 256, 0, stream>>>(rowptr, colv, dinv, Hs, b1, h1s);
    k_agg2<<<nbW, 256, 0, stream>>>(rowptr, colv, dinv, h1s, W2, b2, out);
}